// Round 3
// baseline (388.858 us; speedup 1.0000x reference)
//
#include <hip/hip_runtime.h>
#include <hip/hip_bf16.h>

#define SEQ   8192
#define NB    8
#define EMB   256
#define NHD   8
#define HDM   32
#define LDP   72   // padded LDS row stride in shorts (out_kernel, reg-staged path)

typedef __attribute__((ext_vector_type(8))) short short8;
typedef __attribute__((ext_vector_type(4))) float floatx4;
typedef __attribute__((ext_vector_type(16))) float floatx16;

__device__ __forceinline__ short f2b(float f) {
    __hip_bfloat16 h = __float2bfloat16(f);
    return __builtin_bit_cast(short, h);
}
__device__ __forceinline__ float b2f(short s) {
    unsigned u = (unsigned)(unsigned short)s << 16;
    return __builtin_bit_cast(float, u);
}

// async global->LDS, 16B per lane; LDS dest = wave-uniform base + lane*16 (linear)
__device__ __forceinline__ void gload16(const void* g, void* l) {
    __builtin_amdgcn_global_load_lds(
        (const __attribute__((address_space(1))) unsigned*)g,
        (__attribute__((address_space(3))) unsigned*)l, 16, 0, 0);
}

// ---------------------------------------------------------------------------
// One-shot weight conversion: Wq|Wk|Wv fp32 [256][256] -> bf16, reused 512x.
// ---------------------------------------------------------------------------
__launch_bounds__(256)
__global__ void wconv_kernel(const float* __restrict__ Wq,
                             const float* __restrict__ Wk,
                             const float* __restrict__ Wv,
                             short* __restrict__ Wb) {
    const float* src = (blockIdx.y == 0) ? Wq : (blockIdx.y == 1) ? Wk : Wv;
    const int i = (blockIdx.x * 256 + threadIdx.x) * 8;
    float4 f0 = *(const float4*)(src + i);
    float4 f1 = *(const float4*)(src + i + 4);
    short8 o;
    o[0] = f2b(f0.x); o[1] = f2b(f0.y); o[2] = f2b(f0.z); o[3] = f2b(f0.w);
    o[4] = f2b(f1.x); o[5] = f2b(f1.y); o[6] = f2b(f1.z); o[7] = f2b(f1.w);
    *(short8*)(Wb + (size_t)blockIdx.y * 65536 + i) = o;
}

// ---------------------------------------------------------------------------
// Fused QKV projection — m97 structure (PROVEN safe):
//   per K-chunk: gload_lds stage -> __syncthreads (drains vmcnt 0) ->
//   fragment reads + MFMA -> __syncthreads.
// A = X fp32 in LDS (cvt at fragment read); B = pre-converted bf16 weights.
// Bank conflicts handled per rule #21: linear LDS dest, XOR-swizzled global
// source, same XOR on read (pair-granular for fp32 A, chunk for bf16 B).
// Epilogue identical to the verified Round-0 kernel.
// ---------------------------------------------------------------------------
__launch_bounds__(256)
__global__ void qkv_kernel(const float* __restrict__ qin,
                           const float* __restrict__ kin,
                           const float* __restrict__ vin,
                           const short* __restrict__ Wb,
                           const float* __restrict__ bq,
                           const float* __restrict__ bk,
                           const float* __restrict__ bv,
                           short* __restrict__ Qf, short* __restrict__ Kf,
                           short* __restrict__ Vn,
                           float* __restrict__ Ksum) {
    __shared__ __align__(16) float As[128 * 64];   // 32 KB fp32 X tile (linear)
    __shared__ __align__(16) short Bs[128 * 64];   // 16 KB bf16 W tile (linear)
    __shared__ float colsum[128];

    const int tid  = threadIdx.x;
    const int tm   = blockIdx.x;
    const int tn   = blockIdx.y;
    const int mode = blockIdx.z;
    const int lane = tid & 63;
    const int wave = tid >> 6;
    const int wm   = (wave & 1) << 6;
    const int wn   = (wave >> 1) << 6;
    const int fr   = lane & 15;
    const int fq   = lane >> 4;

    const float* X    = (mode == 0) ? qin : (mode == 1) ? kin : vin;
    const float* bias = (mode == 0) ? bq  : (mode == 1) ? bk  : bv;
    short*       out  = (mode == 0) ? Qf  : (mode == 1) ? Kf  : Vn;

    if (mode == 1 && tid < 128) colsum[tid] = 0.f;

    const float* Xb = X + (size_t)(tm * 128) * EMB;
    const short* Wt = Wb + (size_t)mode * 65536 + (size_t)(tn * 128) * EMB;

    floatx4 acc[4][4];
    #pragma unroll
    for (int i = 0; i < 4; i++)
        #pragma unroll
        for (int j = 0; j < 4; j++)
            #pragma unroll
            for (int r = 0; r < 4; r++) acc[i][j][r] = 0.f;

    for (int kc = 0; kc < 4; kc++) {
        const int kb = kc * 64;
        // A: 128x64 fp32 = 2048 16B-chunks, 8/thread. LDS slot c is linear;
        // source column pair is XOR-swizzled so read-side XOR finds it.
        #pragma unroll
        for (int u = 0; u < 8; u++) {
            const int c   = u * 256 + tid;
            const int row = c >> 4;
            const int q   = c & 15;
            const int col = (((q >> 1) ^ (row & 7)) << 3) + ((q & 1) << 2); // floats
            gload16(Xb + (size_t)row * EMB + kb + col, &As[c * 4]);
        }
        // B: 128x64 bf16 = 1024 16B-chunks, 4/thread.
        #pragma unroll
        for (int u = 0; u < 4; u++) {
            const int c   = u * 256 + tid;
            const int row = c >> 3;
            const int q   = c & 7;
            const int col = ((q ^ (row & 7)) << 3);                         // shorts
            gload16(Wt + (size_t)row * EMB + kb + col, &Bs[c * 8]);
        }
        __syncthreads();   // drains vmcnt(0): all DMA landed before reads
        #pragma unroll
        for (int kk = 0; kk < 64; kk += 32) {
            short8 a[4], b[4];
            #pragma unroll
            for (int i = 0; i < 4; i++) {
                const int row  = wm + i * 16 + fr;
                const int P    = (kk >> 3) + fq;                  // logical pair
                const int base = row * 64 + (((P ^ (row & 7)) << 3));
                float4 x0 = *(const float4*)&As[base];
                float4 x1 = *(const float4*)&As[base + 4];
                short8 t;
                t[0] = f2b(x0.x); t[1] = f2b(x0.y); t[2] = f2b(x0.z); t[3] = f2b(x0.w);
                t[4] = f2b(x1.x); t[5] = f2b(x1.y); t[6] = f2b(x1.z); t[7] = f2b(x1.w);
                a[i] = t;
            }
            #pragma unroll
            for (int j = 0; j < 4; j++) {
                const int row = wn + j * 16 + fr;
                const int qB  = (kk >> 3) + fq;                   // logical chunk
                b[j] = *(const short8*)&Bs[row * 64 + ((qB ^ (row & 7)) << 3)];
            }
            #pragma unroll
            for (int i = 0; i < 4; i++)
                #pragma unroll
                for (int j = 0; j < 4; j++)
                    acc[i][j] = __builtin_amdgcn_mfma_f32_16x16x32_bf16(a[i], b[j], acc[i][j], 0, 0, 0);
        }
        __syncthreads();   // all reads done before next stage overwrites
    }

    const int row0 = tm * 128;
    float ks[4] = {0.f, 0.f, 0.f, 0.f};
    #pragma unroll
    for (int i = 0; i < 4; i++) {
        #pragma unroll
        for (int j = 0; j < 4; j++) {
            const int colg = tn * 128 + wn + j * 16 + fr;
            const float bia = bias[colg];
            #pragma unroll
            for (int rr = 0; rr < 4; rr++) {
                const int rowg = row0 + wm + i * 16 + fq * 4 + rr;
                float v = acc[i][j][rr] + bia;
                if (mode <= 1) v = (v > 0.f) ? (v + 1.f) : __expf(v);   // elu(x)+1
                else           v *= (1.0f / (float)SEQ);
                out[(size_t)rowg * EMB + colg] = f2b(v);
                ks[j] += v;
            }
        }
    }
    if (mode == 1) {
        #pragma unroll
        for (int j = 0; j < 4; j++)
            atomicAdd(&colsum[wn + j * 16 + fr], ks[j]);
        __syncthreads();
        if (tid < 128) {
            const int b = (tm * 128) / SEQ;
            atomicAdd(&Ksum[b * EMB + tn * 128 + tid], colsum[tid]);
        }
    }
}

// ---------------------------------------------------------------------------
// KV partials (byte-identical to the passing Round-0 kernel)
// ---------------------------------------------------------------------------
template <bool ATOMIC>
__launch_bounds__(256)
__global__ void kv_kernel(const short* __restrict__ Kf,
                          const short* __restrict__ Vn,
                          float* __restrict__ dst_base,
                          int kvsp) {
    __shared__ __align__(16) short Kt[32 * 256];
    __shared__ __align__(16) short Vt[32 * 256];

    const int tid  = threadIdx.x;
    const int sp   = blockIdx.x % kvsp;
    const int b    = blockIdx.x / kvsp;
    const int wave = tid >> 6;
    const int lane = tid & 63;
    const int h    = wave * 2 + (lane >> 5);
    const int l5   = lane & 31;
    const int d0   = (l5 >> 2) * 4;
    const int v0   = (l5 & 3) * 8;
    const int chunk = SEQ / kvsp;
    const size_t rowbase = (size_t)(b * SEQ + sp * chunk) * EMB;

    float acc[4][8];
    #pragma unroll
    for (int i = 0; i < 4; i++)
        #pragma unroll
        for (int j = 0; j < 8; j++) acc[i][j] = 0.f;

    for (int t0 = 0; t0 < chunk; t0 += 32) {
        __syncthreads();
        const short* ksrc = Kf + rowbase + (size_t)t0 * EMB;
        const short* vsrc = Vn + rowbase + (size_t)t0 * EMB;
        #pragma unroll
        for (int u = 0; u < 4; u++) {
            const int c   = tid + u * 256;
            const int row = c >> 5;
            const int col = (c & 31) * 8;
            *(short8*)&Kt[row * 256 + col] = *(const short8*)(ksrc + (size_t)row * EMB + col);
            *(short8*)&Vt[row * 256 + col] = *(const short8*)(vsrc + (size_t)row * EMB + col);
        }
        __syncthreads();
        #pragma unroll 4
        for (int s = 0; s < 32; s++) {
            short4 k4 = *(const short4*)&Kt[s * 256 + h * 32 + d0];
            short8 v8 = *(const short8*)&Vt[s * 256 + h * 32 + v0];
            float kf[4] = {b2f(k4.x), b2f(k4.y), b2f(k4.z), b2f(k4.w)};
            float vf[8];
            #pragma unroll
            for (int j = 0; j < 8; j++) vf[j] = b2f(v8[j]);
            #pragma unroll
            for (int i = 0; i < 4; i++)
                #pragma unroll
                for (int j = 0; j < 8; j++) acc[i][j] += kf[i] * vf[j];
        }
    }

    if (ATOMIC) {
        float* dst = dst_base + (size_t)((b * 8 + h) * 1024);
        #pragma unroll
        for (int i = 0; i < 4; i++)
            #pragma unroll
            for (int j = 0; j < 8; j++)
                atomicAdd(&dst[(d0 + i) * 32 + v0 + j], acc[i][j]);
    } else {
        float* dst = dst_base + (size_t)(((size_t)sp * NB + b) * 8 + h) * 1024;
        #pragma unroll
        for (int i = 0; i < 4; i++) {
            float4 lo = make_float4(acc[i][0], acc[i][1], acc[i][2], acc[i][3]);
            float4 hi = make_float4(acc[i][4], acc[i][5], acc[i][6], acc[i][7]);
            *(float4*)&dst[(d0 + i) * 32 + v0]     = lo;
            *(float4*)&dst[(d0 + i) * 32 + v0 + 4] = hi;
        }
    }
}

__launch_bounds__(256)
__global__ void kvred_kernel(const float* __restrict__ KVp,
                             float* __restrict__ KV, int kvsp) {
    const int i = blockIdx.x * 1024 + threadIdx.x * 4;
    float4 s = make_float4(0.f, 0.f, 0.f, 0.f);
    for (int p = 0; p < kvsp; p++) {
        float4 t = *(const float4*)&KVp[(size_t)p * 65536 + i];
        s.x += t.x; s.y += t.y; s.z += t.z; s.w += t.w;
    }
    *(float4*)&KV[i] = s;
}

// ---------------------------------------------------------------------------
// Mt (byte-identical to Round-0)
// ---------------------------------------------------------------------------
__launch_bounds__(64)
__global__ void m_kernel(const float* __restrict__ KV,
                         const float* __restrict__ Wm,
                         short* __restrict__ Mt) {
    const int blk  = blockIdx.x;
    const int e0   = (blk & 7) * 32;
    const int h    = (blk >> 3) & 7;
    const int b    = blk >> 6;
    const int lane = threadIdx.x;
    const int l31  = lane & 31;
    const int q    = lane >> 5;

    floatx16 acc;
    #pragma unroll
    for (int i = 0; i < 16; i++) acc[i] = 0.f;

    #pragma unroll
    for (int kb = 0; kb < 32; kb += 16) {
        const float* ar = KV + (size_t)(((b * 8 + h) * 32 + l31) * 32) + kb + q * 8;
        const float* br = Wm + (size_t)(e0 + l31) * EMB + h * 32 + kb + q * 8;
        short8 a, w;
        #pragma unroll
        for (int t = 0; t < 8; t++) { a[t] = f2b(ar[t]); w[t] = f2b(br[t]); }
        acc = __builtin_amdgcn_mfma_f32_32x32x16_bf16(a, w, acc, 0, 0, 0);
    }

    short* mrow = Mt + (size_t)b * EMB * EMB + (size_t)(e0 + l31) * EMB + h * 32;
    #pragma unroll
    for (int r4 = 0; r4 < 4; r4++) {
        const int dbase = 8 * r4 + 4 * q;
        short4 s4 = make_short4(f2b(acc[r4 * 4 + 0]), f2b(acc[r4 * 4 + 1]),
                                f2b(acc[r4 * 4 + 2]), f2b(acc[r4 * 4 + 3]));
        *(short4*)(mrow + dbase) = s4;
    }
}

// ---------------------------------------------------------------------------
// out_kernel (byte-identical to the passing Round-0 kernel)
// ---------------------------------------------------------------------------
__launch_bounds__(256)
__global__ void out_kernel(const short* __restrict__ Qf,
                           const float* __restrict__ Ksum,
                           const short* __restrict__ Mt,
                           float* __restrict__ Out) {
    __shared__ __align__(16) short As[128 * LDP];
    __shared__ __align__(16) short Bs[128 * LDP];
    __shared__ float zs[128][NHD];
    __shared__ float ksl[EMB];

    const int tid  = threadIdx.x;
    const int tm   = blockIdx.x;
    const int tn   = blockIdx.y;
    const int b    = (tm * 128) / SEQ;
    const int lane = tid & 63;
    const int wave = tid >> 6;
    const int wm   = (wave & 1) << 6;
    const int wn   = (wave >> 1) << 6;
    const int fr   = lane & 15;
    const int fq   = lane >> 4;

    ksl[tid] = Ksum[b * EMB + tid];
    __syncthreads();

    {
        const int t  = tid >> 1;
        const int h0 = (tid & 1) * 4;
        const short* qrow = Qf + (size_t)(tm * 128 + t) * EMB;
        #pragma unroll
        for (int hh = 0; hh < 4; hh++) {
            const int h = h0 + hh;
            float d = 0.f;
            #pragma unroll
            for (int u = 0; u < 8; u++) {
                short4 q4 = *(const short4*)(qrow + h * 32 + 4 * u);
                d += b2f(q4.x) * ksl[h * 32 + 4 * u + 0] + b2f(q4.y) * ksl[h * 32 + 4 * u + 1]
                   + b2f(q4.z) * ksl[h * 32 + 4 * u + 2] + b2f(q4.w) * ksl[h * 32 + 4 * u + 3];
            }
            zs[t][h] = (float)SEQ / (d + 1e-6f);
        }
    }
    __syncthreads();

    floatx4 acc[4][4];
    #pragma unroll
    for (int i = 0; i < 4; i++)
        #pragma unroll
        for (int j = 0; j < 4; j++)
            #pragma unroll
            for (int r = 0; r < 4; r++) acc[i][j][r] = 0.f;

    const short* Ab = Qf + (size_t)(tm * 128) * EMB;
    const short* Bb = Mt + (size_t)b * EMB * EMB + (size_t)(tn * 128) * EMB;

    for (int kc = 0; kc < 4; kc++) {
        const int kb = kc * 64;
        #pragma unroll
        for (int u = 0; u < 4; u++) {
            const int g   = u * 256 + tid;
            const int row = g >> 3;
            const int c8  = (g & 7) * 8;
            const float z = zs[row][(kb + c8) >> 5];
            short8 qv = *(const short8*)(Ab + (size_t)row * EMB + kb + c8);
            short8 oa;
            #pragma unroll
            for (int t = 0; t < 8; t++) oa[t] = f2b(b2f(qv[t]) * z);
            *(short8*)&As[row * LDP + c8] = oa;
            *(short8*)&Bs[row * LDP + c8] = *(const short8*)(Bb + (size_t)row * EMB + kb + c8);
        }
        __syncthreads();
        #pragma unroll
        for (int kk = 0; kk < 64; kk += 32) {
            short8 a[4], bb[4];
            #pragma unroll
            for (int i = 0; i < 4; i++)
                a[i] = *(const short8*)&As[(wm + i * 16 + fr) * LDP + kk + fq * 8];
            #pragma unroll
            for (int j = 0; j < 4; j++)
                bb[j] = *(const short8*)&Bs[(wn + j * 16 + fr) * LDP + kk + fq * 8];
            #pragma unroll
            for (int i = 0; i < 4; i++)
                #pragma unroll
                for (int j = 0; j < 4; j++)
                    acc[i][j] = __builtin_amdgcn_mfma_f32_16x16x32_bf16(a[i], bb[j], acc[i][j], 0, 0, 0);
        }
        __syncthreads();
    }

    const int row0 = tm * 128;
    #pragma unroll
    for (int i = 0; i < 4; i++) {
        #pragma unroll
        for (int j = 0; j < 4; j++) {
            const int colg = tn * 128 + wn + j * 16 + fr;
            #pragma unroll
            for (int rr = 0; rr < 4; rr++) {
                const int rowg = row0 + wm + i * 16 + fq * 4 + rr;
                Out[(size_t)rowg * EMB + colg] = acc[i][j][rr];
            }
        }
    }
}

extern "C" void kernel_launch(void* const* d_in, const int* in_sizes, int n_in,
                              void* d_out, int out_size, void* d_ws, size_t ws_size,
                              hipStream_t stream) {
    (void)in_sizes; (void)n_in; (void)out_size;
    const float* q  = (const float*)d_in[0];
    const float* k  = (const float*)d_in[1];
    const float* v  = (const float*)d_in[2];
    const float* Wq = (const float*)d_in[3];
    const float* bq = (const float*)d_in[4];
    const float* Wk = (const float*)d_in[5];
    const float* bk = (const float*)d_in[6];
    const float* Wv = (const float*)d_in[7];
    const float* bv = (const float*)d_in[8];
    const float* Wm = (const float*)d_in[9];

    char* ws = (char*)d_ws;
    short* Qf   = (short*)(ws);                                   // 32 MB bf16
    short* Kf   = (short*)(ws + 33554432);                        // 32 MB bf16
    short* Vn   = (short*)(ws + 67108864);                        // 32 MB bf16
    float* Ksum = (float*)(ws + 100663296);                       // 8 KB
    float* KV   = (float*)(ws + 100663296 + 8192);                // 256 KB
    short* Mt   = (short*)(ws + 100663296 + 8192 + 262144);       // 1 MB bf16
    // Wb (384 KB) overlays Mt: wconv writes -> qkv reads -> (kv, kvred) ->
    // m_kernel overwrites Mt -> out reads Mt. Strictly stream-ordered.
    short* Wb   = (short*)(ws + 100663296 + 8192 + 262144);
    const size_t kvp_off = 100663296ull + 8192 + 262144 + 1048576;
    float* KVp  = (float*)(ws + kvp_off);                         // kvsp*256 KB

    int kvsp = 0;
    if      (ws_size >= kvp_off + 64ull * 262144) kvsp = 64;
    else if (ws_size >= kvp_off + 32ull * 262144) kvsp = 32;
    else if (ws_size >= kvp_off + 16ull * 262144) kvsp = 16;

    hipMemsetAsync(ws + 100663296, 0, 8192 + 262144, stream);

    dim3 blk(256);
    wconv_kernel<<<dim3(32, 3), blk, 0, stream>>>(Wq, Wk, Wv, Wb);
    qkv_kernel<<<dim3(512, 2, 3), blk, 0, stream>>>(q, k, v, Wb, bq, bk, bv,
                                                    Qf, Kf, Vn, Ksum);

    if (kvsp) {
        kv_kernel<false><<<NB * kvsp, 256, 0, stream>>>(Kf, Vn, KVp, kvsp);
        kvred_kernel<<<64, 256, 0, stream>>>(KVp, KV, kvsp);
    } else {
        kv_kernel<true><<<NB * 16, 256, 0, stream>>>(Kf, Vn, KV, 16);
    }

    m_kernel<<<512, 64, 0, stream>>>(KV, Wm, Mt);
    out_kernel<<<dim3(512, 2), blk, 0, stream>>>(Qf, Ksum, Mt, (float*)d_out);
}

// Round 4
// 385.605 us; speedup vs baseline: 1.0084x; 1.0084x over previous
//
#include <hip/hip_runtime.h>
#include <hip/hip_bf16.h>

#define SEQ   8192
#define NB    8
#define EMB   256
#define NHD   8
#define HDM   32
#define LDP   72   // padded LDS row stride in shorts: 144 B, bank-rotate by 4

typedef __attribute__((ext_vector_type(8))) short short8;
typedef __attribute__((ext_vector_type(4))) float floatx4;
typedef __attribute__((ext_vector_type(16))) float floatx16;

__device__ __forceinline__ short f2b(float f) {
    __hip_bfloat16 h = __float2bfloat16(f);
    return __builtin_bit_cast(short, h);
}
__device__ __forceinline__ float b2f(short s) {
    unsigned u = (unsigned)(unsigned short)s << 16;
    return __builtin_bit_cast(float, u);
}

// Barrier that does NOT drain vmcnt: safe when the only cross-thread state is
// LDS (ordered by lgkmcnt(0)). In-flight global->REGISTER loads are private
// and legitimately survive the barrier — this is the whole pipeline trick.
__device__ __forceinline__ void lds_barrier() {
    asm volatile("s_waitcnt lgkmcnt(0)" ::: "memory");
    __builtin_amdgcn_sched_barrier(0);
    __builtin_amdgcn_s_barrier();
    __builtin_amdgcn_sched_barrier(0);
}

// ---------------------------------------------------------------------------
// One-shot weight conversion: Wq|Wk|Wv fp32 [256][256] -> bf16, reused 512x.
// ---------------------------------------------------------------------------
__launch_bounds__(256)
__global__ void wconv_kernel(const float* __restrict__ Wq,
                             const float* __restrict__ Wk,
                             const float* __restrict__ Wv,
                             short* __restrict__ Wb) {
    const float* src = (blockIdx.y == 0) ? Wq : (blockIdx.y == 1) ? Wk : Wv;
    const int i = (blockIdx.x * 256 + threadIdx.x) * 8;
    float4 f0 = *(const float4*)(src + i);
    float4 f1 = *(const float4*)(src + i + 4);
    short8 o;
    o[0] = f2b(f0.x); o[1] = f2b(f0.y); o[2] = f2b(f0.z); o[3] = f2b(f0.w);
    o[4] = f2b(f1.x); o[5] = f2b(f1.y); o[6] = f2b(f1.z); o[7] = f2b(f1.w);
    *(short8*)(Wb + (size_t)blockIdx.y * 65536 + i) = o;
}

// ---------------------------------------------------------------------------
// Fused QKV projection — round-0 reg-staged structure + register-prefetch
// pipeline: chunk k+1's global loads are issued after chunk k's ds_writes and
// stay in flight across the (non-draining) lds_barrier + compute phase.
// Compiler-managed counted vmcnt via register deps; no manual vmcnt numbers.
// W pre-converted to bf16 (wconv) -> staging is a pure short8 copy.
// ---------------------------------------------------------------------------
__launch_bounds__(256, 3)
__global__ void qkv_kernel(const float* __restrict__ qin,
                           const float* __restrict__ kin,
                           const float* __restrict__ vin,
                           const short* __restrict__ Wb,
                           const float* __restrict__ bq,
                           const float* __restrict__ bk,
                           const float* __restrict__ bv,
                           short* __restrict__ Qf, short* __restrict__ Kf,
                           short* __restrict__ Vn,
                           float* __restrict__ Ksum) {
    __shared__ __align__(16) short As[128 * LDP];
    __shared__ __align__(16) short Bs[128 * LDP];
    __shared__ float colsum[128];

    const int tid  = threadIdx.x;
    const int tm   = blockIdx.x;
    const int tn   = blockIdx.y;
    const int mode = blockIdx.z;
    const int lane = tid & 63;
    const int wave = tid >> 6;
    const int wm   = (wave & 1) << 6;
    const int wn   = (wave >> 1) << 6;
    const int fr   = lane & 15;
    const int fq   = lane >> 4;

    const float* X    = (mode == 0) ? qin : (mode == 1) ? kin : vin;
    const float* bias = (mode == 0) ? bq  : (mode == 1) ? bk  : bv;
    short*       out  = (mode == 0) ? Qf  : (mode == 1) ? Kf  : Vn;

    if (mode == 1 && tid < 128) colsum[tid] = 0.f;

    const float* Xb = X + (size_t)(tm * 128) * EMB;
    const short* Wt = Wb + (size_t)mode * 65536 + (size_t)(tn * 128) * EMB;

    floatx4 acc[4][4];
    #pragma unroll
    for (int i = 0; i < 4; i++)
        #pragma unroll
        for (int j = 0; j < 4; j++)
            #pragma unroll
            for (int r = 0; r < 4; r++) acc[i][j][r] = 0.f;

    float4 pa[8];   // prefetched A chunk (fp32)
    short8 pw[4];   // prefetched W chunk (bf16)

    auto loadA = [&](int kc) {
        const int kb = kc * 64;
        #pragma unroll
        for (int u = 0; u < 8; u++) {
            const int g = u * 256 + tid;
            pa[u] = *(const float4*)(Xb + (size_t)(g >> 4) * EMB + kb + (g & 15) * 4);
        }
    };
    auto loadW = [&](int kc) {
        const int kb = kc * 64;
        #pragma unroll
        for (int u = 0; u < 4; u++) {
            const int g = u * 256 + tid;
            pw[u] = *(const short8*)(Wt + (size_t)(g >> 3) * EMB + kb + (g & 7) * 8);
        }
    };

    loadA(0); loadW(0);

    for (int kc = 0; kc < 4; kc++) {
        // write current prefetch regs to LDS (compiler inserts the vmcnt waits)
        #pragma unroll
        for (int u = 0; u < 8; u++) {
            const int g = u * 256 + tid;
            const int row = g >> 4, c4 = (g & 15) * 4;
            *(short4*)&As[row * LDP + c4] =
                make_short4(f2b(pa[u].x), f2b(pa[u].y), f2b(pa[u].z), f2b(pa[u].w));
        }
        #pragma unroll
        for (int u = 0; u < 4; u++) {
            const int g = u * 256 + tid;
            *(short8*)&Bs[(g >> 3) * LDP + (g & 7) * 8] = pw[u];
        }
        // issue next chunk's loads; they stay in flight through barrier+compute
        if (kc < 3) { loadA(kc + 1); loadW(kc + 1); }
        lds_barrier();      // all waves' ds_writes complete; vmcnt NOT drained

        #pragma unroll
        for (int kk = 0; kk < 64; kk += 32) {
            short8 a[4], b[4];
            #pragma unroll
            for (int i = 0; i < 4; i++)
                a[i] = *(const short8*)&As[(wm + i * 16 + fr) * LDP + kk + fq * 8];
            #pragma unroll
            for (int j = 0; j < 4; j++)
                b[j] = *(const short8*)&Bs[(wn + j * 16 + fr) * LDP + kk + fq * 8];
            #pragma unroll
            for (int i = 0; i < 4; i++)
                #pragma unroll
                for (int j = 0; j < 4; j++)
                    acc[i][j] = __builtin_amdgcn_mfma_f32_16x16x32_bf16(a[i], b[j], acc[i][j], 0, 0, 0);
        }
        lds_barrier();      // all waves' ds_reads complete before next overwrite
    }

    const int row0 = tm * 128;
    float ks[4] = {0.f, 0.f, 0.f, 0.f};
    #pragma unroll
    for (int i = 0; i < 4; i++) {
        #pragma unroll
        for (int j = 0; j < 4; j++) {
            const int colg = tn * 128 + wn + j * 16 + fr;
            const float bia = bias[colg];
            #pragma unroll
            for (int rr = 0; rr < 4; rr++) {
                const int rowg = row0 + wm + i * 16 + fq * 4 + rr;
                float v = acc[i][j][rr] + bia;
                if (mode <= 1) v = (v > 0.f) ? (v + 1.f) : __expf(v);   // elu(x)+1
                else           v *= (1.0f / (float)SEQ);
                out[(size_t)rowg * EMB + colg] = f2b(v);
                ks[j] += v;
            }
        }
    }
    if (mode == 1) {
        #pragma unroll
        for (int j = 0; j < 4; j++)
            atomicAdd(&colsum[wn + j * 16 + fr], ks[j]);
        __syncthreads();
        if (tid < 128) {
            const int b = (tm * 128) / SEQ;
            atomicAdd(&Ksum[b * EMB + tn * 128 + tid], colsum[tid]);
        }
    }
}

// ---------------------------------------------------------------------------
// KV partials — same register-prefetch pipeline (math/output identical R0).
// ---------------------------------------------------------------------------
template <bool ATOMIC>
__launch_bounds__(256)
__global__ void kv_kernel(const short* __restrict__ Kf,
                          const short* __restrict__ Vn,
                          float* __restrict__ dst_base,
                          int kvsp) {
    __shared__ __align__(16) short Kt[32 * 256];
    __shared__ __align__(16) short Vt[32 * 256];

    const int tid  = threadIdx.x;
    const int sp   = blockIdx.x % kvsp;
    const int b    = blockIdx.x / kvsp;
    const int wave = tid >> 6;
    const int lane = tid & 63;
    const int h    = wave * 2 + (lane >> 5);
    const int l5   = lane & 31;
    const int d0   = (l5 >> 2) * 4;
    const int v0   = (l5 & 3) * 8;
    const int chunk = SEQ / kvsp;
    const size_t rowbase = (size_t)(b * SEQ + sp * chunk) * EMB;

    float acc[4][8];
    #pragma unroll
    for (int i = 0; i < 4; i++)
        #pragma unroll
        for (int j = 0; j < 8; j++) acc[i][j] = 0.f;

    short8 pk[4], pv[4];
    auto loadKV = [&](int t0) {
        const short* ksrc = Kf + rowbase + (size_t)t0 * EMB;
        const short* vsrc = Vn + rowbase + (size_t)t0 * EMB;
        #pragma unroll
        for (int u = 0; u < 4; u++) {
            const int c   = tid + u * 256;
            const int row = c >> 5;
            const int col = (c & 31) * 8;
            pk[u] = *(const short8*)(ksrc + (size_t)row * EMB + col);
            pv[u] = *(const short8*)(vsrc + (size_t)row * EMB + col);
        }
    };

    loadKV(0);
    for (int t0 = 0; t0 < chunk; t0 += 32) {
        #pragma unroll
        for (int u = 0; u < 4; u++) {
            const int c   = tid + u * 256;
            const int row = c >> 5;
            const int col = (c & 31) * 8;
            *(short8*)&Kt[row * 256 + col] = pk[u];
            *(short8*)&Vt[row * 256 + col] = pv[u];
        }
        if (t0 + 32 < chunk) loadKV(t0 + 32);
        lds_barrier();
        #pragma unroll 4
        for (int s = 0; s < 32; s++) {
            short4 k4 = *(const short4*)&Kt[s * 256 + h * 32 + d0];
            short8 v8 = *(const short8*)&Vt[s * 256 + h * 32 + v0];
            float kf[4] = {b2f(k4.x), b2f(k4.y), b2f(k4.z), b2f(k4.w)};
            float vf[8];
            #pragma unroll
            for (int j = 0; j < 8; j++) vf[j] = b2f(v8[j]);
            #pragma unroll
            for (int i = 0; i < 4; i++)
                #pragma unroll
                for (int j = 0; j < 8; j++) acc[i][j] += kf[i] * vf[j];
        }
        lds_barrier();
    }

    if (ATOMIC) {
        float* dst = dst_base + (size_t)((b * 8 + h) * 1024);
        #pragma unroll
        for (int i = 0; i < 4; i++)
            #pragma unroll
            for (int j = 0; j < 8; j++)
                atomicAdd(&dst[(d0 + i) * 32 + v0 + j], acc[i][j]);
    } else {
        float* dst = dst_base + (size_t)(((size_t)sp * NB + b) * 8 + h) * 1024;
        #pragma unroll
        for (int i = 0; i < 4; i++) {
            float4 lo = make_float4(acc[i][0], acc[i][1], acc[i][2], acc[i][3]);
            float4 hi = make_float4(acc[i][4], acc[i][5], acc[i][6], acc[i][7]);
            *(float4*)&dst[(d0 + i) * 32 + v0]     = lo;
            *(float4*)&dst[(d0 + i) * 32 + v0 + 4] = hi;
        }
    }
}

__launch_bounds__(256)
__global__ void kvred_kernel(const float* __restrict__ KVp,
                             float* __restrict__ KV, int kvsp) {
    const int i = blockIdx.x * 1024 + threadIdx.x * 4;
    float4 s = make_float4(0.f, 0.f, 0.f, 0.f);
    for (int p = 0; p < kvsp; p++) {
        float4 t = *(const float4*)&KVp[(size_t)p * 65536 + i];
        s.x += t.x; s.y += t.y; s.z += t.z; s.w += t.w;
    }
    *(float4*)&KV[i] = s;
}

// ---------------------------------------------------------------------------
// Mt (byte-identical to Round-0)
// ---------------------------------------------------------------------------
__launch_bounds__(64)
__global__ void m_kernel(const float* __restrict__ KV,
                         const float* __restrict__ Wm,
                         short* __restrict__ Mt) {
    const int blk  = blockIdx.x;
    const int e0   = (blk & 7) * 32;
    const int h    = (blk >> 3) & 7;
    const int b    = blk >> 6;
    const int lane = threadIdx.x;
    const int l31  = lane & 31;
    const int q    = lane >> 5;

    floatx16 acc;
    #pragma unroll
    for (int i = 0; i < 16; i++) acc[i] = 0.f;

    #pragma unroll
    for (int kb = 0; kb < 32; kb += 16) {
        const float* ar = KV + (size_t)(((b * 8 + h) * 32 + l31) * 32) + kb + q * 8;
        const float* br = Wm + (size_t)(e0 + l31) * EMB + h * 32 + kb + q * 8;
        short8 a, w;
        #pragma unroll
        for (int t = 0; t < 8; t++) { a[t] = f2b(ar[t]); w[t] = f2b(br[t]); }
        acc = __builtin_amdgcn_mfma_f32_32x32x16_bf16(a, w, acc, 0, 0, 0);
    }

    short* mrow = Mt + (size_t)b * EMB * EMB + (size_t)(e0 + l31) * EMB + h * 32;
    #pragma unroll
    for (int r4 = 0; r4 < 4; r4++) {
        const int dbase = 8 * r4 + 4 * q;
        short4 s4 = make_short4(f2b(acc[r4 * 4 + 0]), f2b(acc[r4 * 4 + 1]),
                                f2b(acc[r4 * 4 + 2]), f2b(acc[r4 * 4 + 3]));
        *(short4*)(mrow + dbase) = s4;
    }
}

// ---------------------------------------------------------------------------
// out_kernel — round-0 structure + register-prefetch pipeline (staging only
// changed; zs precompute and epilogue byte-identical to Round-0).
// ---------------------------------------------------------------------------
__launch_bounds__(256, 3)
__global__ void out_kernel(const short* __restrict__ Qf,
                           const float* __restrict__ Ksum,
                           const short* __restrict__ Mt,
                           float* __restrict__ Out) {
    __shared__ __align__(16) short As[128 * LDP];
    __shared__ __align__(16) short Bs[128 * LDP];
    __shared__ float zs[128][NHD];
    __shared__ float ksl[EMB];

    const int tid  = threadIdx.x;
    const int tm   = blockIdx.x;
    const int tn   = blockIdx.y;
    const int b    = (tm * 128) / SEQ;
    const int lane = tid & 63;
    const int wave = tid >> 6;
    const int wm   = (wave & 1) << 6;
    const int wn   = (wave >> 1) << 6;
    const int fr   = lane & 15;
    const int fq   = lane >> 4;

    ksl[tid] = Ksum[b * EMB + tid];
    __syncthreads();

    {
        const int t  = tid >> 1;
        const int h0 = (tid & 1) * 4;
        const short* qrow = Qf + (size_t)(tm * 128 + t) * EMB;
        #pragma unroll
        for (int hh = 0; hh < 4; hh++) {
            const int h = h0 + hh;
            float d = 0.f;
            #pragma unroll
            for (int u = 0; u < 8; u++) {
                short4 q4 = *(const short4*)(qrow + h * 32 + 4 * u);
                d += b2f(q4.x) * ksl[h * 32 + 4 * u + 0] + b2f(q4.y) * ksl[h * 32 + 4 * u + 1]
                   + b2f(q4.z) * ksl[h * 32 + 4 * u + 2] + b2f(q4.w) * ksl[h * 32 + 4 * u + 3];
            }
            zs[t][h] = (float)SEQ / (d + 1e-6f);
        }
    }
    __syncthreads();

    floatx4 acc[4][4];
    #pragma unroll
    for (int i = 0; i < 4; i++)
        #pragma unroll
        for (int j = 0; j < 4; j++)
            #pragma unroll
            for (int r = 0; r < 4; r++) acc[i][j][r] = 0.f;

    const short* Ab = Qf + (size_t)(tm * 128) * EMB;
    const short* Bb = Mt + (size_t)b * EMB * EMB + (size_t)(tn * 128) * EMB;

    short8 pq[4], pm[4];
    auto loadQM = [&](int kc) {
        const int kb = kc * 64;
        #pragma unroll
        for (int u = 0; u < 4; u++) {
            const int g = u * 256 + tid;
            const int row = g >> 3, c8 = (g & 7) * 8;
            pq[u] = *(const short8*)(Ab + (size_t)row * EMB + kb + c8);
            pm[u] = *(const short8*)(Bb + (size_t)row * EMB + kb + c8);
        }
    };

    loadQM(0);
    for (int kc = 0; kc < 4; kc++) {
        const int kb = kc * 64;
        #pragma unroll
        for (int u = 0; u < 4; u++) {
            const int g = u * 256 + tid;
            const int row = g >> 3, c8 = (g & 7) * 8;
            const float z = zs[row][(kb + c8) >> 5];
            short8 oa;
            #pragma unroll
            for (int t = 0; t < 8; t++) oa[t] = f2b(b2f(pq[u][t]) * z);
            *(short8*)&As[row * LDP + c8] = oa;
            *(short8*)&Bs[row * LDP + c8] = pm[u];
        }
        if (kc < 3) loadQM(kc + 1);
        lds_barrier();
        #pragma unroll
        for (int kk = 0; kk < 64; kk += 32) {
            short8 a[4], bb[4];
            #pragma unroll
            for (int i = 0; i < 4; i++)
                a[i] = *(const short8*)&As[(wm + i * 16 + fr) * LDP + kk + fq * 8];
            #pragma unroll
            for (int j = 0; j < 4; j++)
                bb[j] = *(const short8*)&Bs[(wn + j * 16 + fr) * LDP + kk + fq * 8];
            #pragma unroll
            for (int i = 0; i < 4; i++)
                #pragma unroll
                for (int j = 0; j < 4; j++)
                    acc[i][j] = __builtin_amdgcn_mfma_f32_16x16x32_bf16(a[i], bb[j], acc[i][j], 0, 0, 0);
        }
        lds_barrier();
    }

    const int row0 = tm * 128;
    #pragma unroll
    for (int i = 0; i < 4; i++) {
        #pragma unroll
        for (int j = 0; j < 4; j++) {
            const int colg = tn * 128 + wn + j * 16 + fr;
            #pragma unroll
            for (int rr = 0; rr < 4; rr++) {
                const int rowg = row0 + wm + i * 16 + fq * 4 + rr;
                Out[(size_t)rowg * EMB + colg] = acc[i][j][rr];
            }
        }
    }
}

extern "C" void kernel_launch(void* const* d_in, const int* in_sizes, int n_in,
                              void* d_out, int out_size, void* d_ws, size_t ws_size,
                              hipStream_t stream) {
    (void)in_sizes; (void)n_in; (void)out_size;
    const float* q  = (const float*)d_in[0];
    const float* k  = (const float*)d_in[1];
    const float* v  = (const float*)d_in[2];
    const float* Wq = (const float*)d_in[3];
    const float* bq = (const float*)d_in[4];
    const float* Wk = (const float*)d_in[5];
    const float* bk = (const float*)d_in[6];
    const float* Wv = (const float*)d_in[7];
    const float* bv = (const float*)d_in[8];
    const float* Wm = (const float*)d_in[9];

    char* ws = (char*)d_ws;
    short* Qf   = (short*)(ws);                                   // 32 MB bf16
    short* Kf   = (short*)(ws + 33554432);                        // 32 MB bf16
    short* Vn   = (short*)(ws + 67108864);                        // 32 MB bf16
    float* Ksum = (float*)(ws + 100663296);                       // 8 KB
    float* KV   = (float*)(ws + 100663296 + 8192);                // 256 KB
    short* Mt   = (short*)(ws + 100663296 + 8192 + 262144);       // 1 MB bf16
    // Wb (384 KB) overlays Mt: wconv writes -> qkv reads -> m_kernel overwrites
    // Mt -> out reads Mt. Strictly stream-ordered.
    short* Wb   = (short*)(ws + 100663296 + 8192 + 262144);
    const size_t kvp_off = 100663296ull + 8192 + 262144 + 1048576;
    float* KVp  = (float*)(ws + kvp_off);                         // kvsp*256 KB

    int kvsp = 0;
    if      (ws_size >= kvp_off + 64ull * 262144) kvsp = 64;
    else if (ws_size >= kvp_off + 32ull * 262144) kvsp = 32;
    else if (ws_size >= kvp_off + 16ull * 262144) kvsp = 16;

    hipMemsetAsync(ws + 100663296, 0, 8192 + 262144, stream);

    dim3 blk(256);
    wconv_kernel<<<dim3(32, 3), blk, 0, stream>>>(Wq, Wk, Wv, Wb);
    qkv_kernel<<<dim3(512, 2, 3), blk, 0, stream>>>(q, k, v, Wb, bq, bk, bv,
                                                    Qf, Kf, Vn, Ksum);

    if (kvsp) {
        kv_kernel<false><<<NB * kvsp, 256, 0, stream>>>(Kf, Vn, KVp, kvsp);
        kvred_kernel<<<64, 256, 0, stream>>>(KVp, KV, kvsp);
    } else {
        kv_kernel<true><<<NB * 16, 256, 0, stream>>>(Kf, Vn, KV, 16);
    }

    m_kernel<<<512, 64, 0, stream>>>(KV, Wm, Mt);
    out_kernel<<<dim3(512, 2), blk, 0, stream>>>(Qf, Ksum, Mt, (float*)d_out);
}

// Round 5
// 344.209 us; speedup vs baseline: 1.1297x; 1.1203x over previous
//
#include <hip/hip_runtime.h>
#include <hip/hip_bf16.h>

#define SEQ   8192
#define NB    8
#define EMB   256
#define NHD   8
#define HDM   32
#define LDP   72   // padded LDS row stride in shorts: 144 B, bank-rotate by 4

typedef __attribute__((ext_vector_type(8))) short short8;
typedef __attribute__((ext_vector_type(4))) float floatx4;
typedef __attribute__((ext_vector_type(16))) float floatx16;

__device__ __forceinline__ short f2b(float f) {
    __hip_bfloat16 h = __float2bfloat16(f);
    return __builtin_bit_cast(short, h);
}
__device__ __forceinline__ float b2f(short s) {
    unsigned u = (unsigned)(unsigned short)s << 16;
    return __builtin_bit_cast(float, u);
}

// Barrier that does NOT drain vmcnt: safe when the only cross-thread state is
// LDS (ordered by lgkmcnt(0)). In-flight global->REGISTER loads are private
// and legitimately survive the barrier — this is the whole pipeline trick.
__device__ __forceinline__ void lds_barrier() {
    asm volatile("s_waitcnt lgkmcnt(0)" ::: "memory");
    __builtin_amdgcn_sched_barrier(0);
    __builtin_amdgcn_s_barrier();
    __builtin_amdgcn_sched_barrier(0);
}

// ---------------------------------------------------------------------------
// One-shot weight conversion: Wq|Wk|Wv fp32 [256][256] -> bf16, reused 512x.
// ---------------------------------------------------------------------------
__launch_bounds__(256)
__global__ void wconv_kernel(const float* __restrict__ Wq,
                             const float* __restrict__ Wk,
                             const float* __restrict__ Wv,
                             short* __restrict__ Wb) {
    const float* src = (blockIdx.y == 0) ? Wq : (blockIdx.y == 1) ? Wk : Wv;
    const int i = (blockIdx.x * 256 + threadIdx.x) * 8;
    float4 f0 = *(const float4*)(src + i);
    float4 f1 = *(const float4*)(src + i + 4);
    short8 o;
    o[0] = f2b(f0.x); o[1] = f2b(f0.y); o[2] = f2b(f0.z); o[3] = f2b(f0.w);
    o[4] = f2b(f1.x); o[5] = f2b(f1.y); o[6] = f2b(f1.z); o[7] = f2b(f1.w);
    *(short8*)(Wb + (size_t)blockIdx.y * 65536 + i) = o;
}

// ---------------------------------------------------------------------------
// Fused QKV projection — register-prefetch pipeline (R4 structure).
// R5 changes: (1) plain __launch_bounds__(256) — the (256,3) occupancy bound
// made the allocator spill the 48-reg prefetch state to scratch, which
// round-tripped ~150 MB through HBM (R4: WRITE_SIZE doubled, VGPR 84 < live
// state). (2) grid transposed to (tn, tm, mode) so the two tn-blocks sharing
// an A-tile are dispatch-adjacent -> same XCD -> A re-read is an L2 hit and
// the two column-halves of each output row go dirty together.
// ---------------------------------------------------------------------------
__launch_bounds__(256)
__global__ void qkv_kernel(const float* __restrict__ qin,
                           const float* __restrict__ kin,
                           const float* __restrict__ vin,
                           const short* __restrict__ Wb,
                           const float* __restrict__ bq,
                           const float* __restrict__ bk,
                           const float* __restrict__ bv,
                           short* __restrict__ Qf, short* __restrict__ Kf,
                           short* __restrict__ Vn,
                           float* __restrict__ Ksum) {
    __shared__ __align__(16) short As[128 * LDP];
    __shared__ __align__(16) short Bs[128 * LDP];
    __shared__ float colsum[128];

    const int tid  = threadIdx.x;
    const int tn   = blockIdx.x;    // fast dim: the 2 N-halves of one tile
    const int tm   = blockIdx.y;
    const int mode = blockIdx.z;
    const int lane = tid & 63;
    const int wave = tid >> 6;
    const int wm   = (wave & 1) << 6;
    const int wn   = (wave >> 1) << 6;
    const int fr   = lane & 15;
    const int fq   = lane >> 4;

    const float* X    = (mode == 0) ? qin : (mode == 1) ? kin : vin;
    const float* bias = (mode == 0) ? bq  : (mode == 1) ? bk  : bv;
    short*       out  = (mode == 0) ? Qf  : (mode == 1) ? Kf  : Vn;

    if (mode == 1 && tid < 128) colsum[tid] = 0.f;

    const float* Xb = X + (size_t)(tm * 128) * EMB;
    const short* Wt = Wb + (size_t)mode * 65536 + (size_t)(tn * 128) * EMB;

    floatx4 acc[4][4];
    #pragma unroll
    for (int i = 0; i < 4; i++)
        #pragma unroll
        for (int j = 0; j < 4; j++)
            #pragma unroll
            for (int r = 0; r < 4; r++) acc[i][j][r] = 0.f;

    float4 pa[8];   // prefetched A chunk (fp32)
    short8 pw[4];   // prefetched W chunk (bf16)

    auto loadA = [&](int kc) {
        const int kb = kc * 64;
        #pragma unroll
        for (int u = 0; u < 8; u++) {
            const int g = u * 256 + tid;
            pa[u] = *(const float4*)(Xb + (size_t)(g >> 4) * EMB + kb + (g & 15) * 4);
        }
    };
    auto loadW = [&](int kc) {
        const int kb = kc * 64;
        #pragma unroll
        for (int u = 0; u < 4; u++) {
            const int g = u * 256 + tid;
            pw[u] = *(const short8*)(Wt + (size_t)(g >> 3) * EMB + kb + (g & 7) * 8);
        }
    };

    loadA(0); loadW(0);

    for (int kc = 0; kc < 4; kc++) {
        // write current prefetch regs to LDS (compiler inserts the vmcnt waits)
        #pragma unroll
        for (int u = 0; u < 8; u++) {
            const int g = u * 256 + tid;
            const int row = g >> 4, c4 = (g & 15) * 4;
            *(short4*)&As[row * LDP + c4] =
                make_short4(f2b(pa[u].x), f2b(pa[u].y), f2b(pa[u].z), f2b(pa[u].w));
        }
        #pragma unroll
        for (int u = 0; u < 4; u++) {
            const int g = u * 256 + tid;
            *(short8*)&Bs[(g >> 3) * LDP + (g & 7) * 8] = pw[u];
        }
        // issue next chunk's loads; they stay in flight through barrier+compute
        if (kc < 3) { loadA(kc + 1); loadW(kc + 1); }
        lds_barrier();      // all waves' ds_writes complete; vmcnt NOT drained

        #pragma unroll
        for (int kk = 0; kk < 64; kk += 32) {
            short8 a[4], b[4];
            #pragma unroll
            for (int i = 0; i < 4; i++)
                a[i] = *(const short8*)&As[(wm + i * 16 + fr) * LDP + kk + fq * 8];
            #pragma unroll
            for (int j = 0; j < 4; j++)
                b[j] = *(const short8*)&Bs[(wn + j * 16 + fr) * LDP + kk + fq * 8];
            #pragma unroll
            for (int i = 0; i < 4; i++)
                #pragma unroll
                for (int j = 0; j < 4; j++)
                    acc[i][j] = __builtin_amdgcn_mfma_f32_16x16x32_bf16(a[i], b[j], acc[i][j], 0, 0, 0);
        }
        lds_barrier();      // all waves' ds_reads complete before next overwrite
    }

    const int row0 = tm * 128;
    float ks[4] = {0.f, 0.f, 0.f, 0.f};
    #pragma unroll
    for (int i = 0; i < 4; i++) {
        #pragma unroll
        for (int j = 0; j < 4; j++) {
            const int colg = tn * 128 + wn + j * 16 + fr;
            const float bia = bias[colg];
            #pragma unroll
            for (int rr = 0; rr < 4; rr++) {
                const int rowg = row0 + wm + i * 16 + fq * 4 + rr;
                float v = acc[i][j][rr] + bia;
                if (mode <= 1) v = (v > 0.f) ? (v + 1.f) : __expf(v);   // elu(x)+1
                else           v *= (1.0f / (float)SEQ);
                out[(size_t)rowg * EMB + colg] = f2b(v);
                ks[j] += v;
            }
        }
    }
    if (mode == 1) {
        #pragma unroll
        for (int j = 0; j < 4; j++)
            atomicAdd(&colsum[wn + j * 16 + fr], ks[j]);
        __syncthreads();
        if (tid < 128) {
            const int b = (tm * 128) / SEQ;
            atomicAdd(&Ksum[b * EMB + tn * 128 + tid], colsum[tid]);
        }
    }
}

// ---------------------------------------------------------------------------
// KV partials — register-prefetch pipeline (unchanged from R4, passed).
// ---------------------------------------------------------------------------
template <bool ATOMIC>
__launch_bounds__(256)
__global__ void kv_kernel(const short* __restrict__ Kf,
                          const short* __restrict__ Vn,
                          float* __restrict__ dst_base,
                          int kvsp) {
    __shared__ __align__(16) short Kt[32 * 256];
    __shared__ __align__(16) short Vt[32 * 256];

    const int tid  = threadIdx.x;
    const int sp   = blockIdx.x % kvsp;
    const int b    = blockIdx.x / kvsp;
    const int wave = tid >> 6;
    const int lane = tid & 63;
    const int h    = wave * 2 + (lane >> 5);
    const int l5   = lane & 31;
    const int d0   = (l5 >> 2) * 4;
    const int v0   = (l5 & 3) * 8;
    const int chunk = SEQ / kvsp;
    const size_t rowbase = (size_t)(b * SEQ + sp * chunk) * EMB;

    float acc[4][8];
    #pragma unroll
    for (int i = 0; i < 4; i++)
        #pragma unroll
        for (int j = 0; j < 8; j++) acc[i][j] = 0.f;

    short8 pk[4], pv[4];
    auto loadKV = [&](int t0) {
        const short* ksrc = Kf + rowbase + (size_t)t0 * EMB;
        const short* vsrc = Vn + rowbase + (size_t)t0 * EMB;
        #pragma unroll
        for (int u = 0; u < 4; u++) {
            const int c   = tid + u * 256;
            const int row = c >> 5;
            const int col = (c & 31) * 8;
            pk[u] = *(const short8*)(ksrc + (size_t)row * EMB + col);
            pv[u] = *(const short8*)(vsrc + (size_t)row * EMB + col);
        }
    };

    loadKV(0);
    for (int t0 = 0; t0 < chunk; t0 += 32) {
        #pragma unroll
        for (int u = 0; u < 4; u++) {
            const int c   = tid + u * 256;
            const int row = c >> 5;
            const int col = (c & 31) * 8;
            *(short8*)&Kt[row * 256 + col] = pk[u];
            *(short8*)&Vt[row * 256 + col] = pv[u];
        }
        if (t0 + 32 < chunk) loadKV(t0 + 32);
        lds_barrier();
        #pragma unroll 4
        for (int s = 0; s < 32; s++) {
            short4 k4 = *(const short4*)&Kt[s * 256 + h * 32 + d0];
            short8 v8 = *(const short8*)&Vt[s * 256 + h * 32 + v0];
            float kf[4] = {b2f(k4.x), b2f(k4.y), b2f(k4.z), b2f(k4.w)};
            float vf[8];
            #pragma unroll
            for (int j = 0; j < 8; j++) vf[j] = b2f(v8[j]);
            #pragma unroll
            for (int i = 0; i < 4; i++)
                #pragma unroll
                for (int j = 0; j < 8; j++) acc[i][j] += kf[i] * vf[j];
        }
        lds_barrier();
    }

    if (ATOMIC) {
        float* dst = dst_base + (size_t)((b * 8 + h) * 1024);
        #pragma unroll
        for (int i = 0; i < 4; i++)
            #pragma unroll
            for (int j = 0; j < 8; j++)
                atomicAdd(&dst[(d0 + i) * 32 + v0 + j], acc[i][j]);
    } else {
        float* dst = dst_base + (size_t)(((size_t)sp * NB + b) * 8 + h) * 1024;
        #pragma unroll
        for (int i = 0; i < 4; i++) {
            float4 lo = make_float4(acc[i][0], acc[i][1], acc[i][2], acc[i][3]);
            float4 hi = make_float4(acc[i][4], acc[i][5], acc[i][6], acc[i][7]);
            *(float4*)&dst[(d0 + i) * 32 + v0]     = lo;
            *(float4*)&dst[(d0 + i) * 32 + v0 + 4] = hi;
        }
    }
}

__launch_bounds__(256)
__global__ void kvred_kernel(const float* __restrict__ KVp,
                             float* __restrict__ KV, int kvsp) {
    const int i = blockIdx.x * 1024 + threadIdx.x * 4;
    float4 s = make_float4(0.f, 0.f, 0.f, 0.f);
    for (int p = 0; p < kvsp; p++) {
        float4 t = *(const float4*)&KVp[(size_t)p * 65536 + i];
        s.x += t.x; s.y += t.y; s.z += t.z; s.w += t.w;
    }
    *(float4*)&KV[i] = s;
}

// ---------------------------------------------------------------------------
// Mt (byte-identical to Round-0)
// ---------------------------------------------------------------------------
__launch_bounds__(64)
__global__ void m_kernel(const float* __restrict__ KV,
                         const float* __restrict__ Wm,
                         short* __restrict__ Mt) {
    const int blk  = blockIdx.x;
    const int e0   = (blk & 7) * 32;
    const int h    = (blk >> 3) & 7;
    const int b    = blk >> 6;
    const int lane = threadIdx.x;
    const int l31  = lane & 31;
    const int q    = lane >> 5;

    floatx16 acc;
    #pragma unroll
    for (int i = 0; i < 16; i++) acc[i] = 0.f;

    #pragma unroll
    for (int kb = 0; kb < 32; kb += 16) {
        const float* ar = KV + (size_t)(((b * 8 + h) * 32 + l31) * 32) + kb + q * 8;
        const float* br = Wm + (size_t)(e0 + l31) * EMB + h * 32 + kb + q * 8;
        short8 a, w;
        #pragma unroll
        for (int t = 0; t < 8; t++) { a[t] = f2b(ar[t]); w[t] = f2b(br[t]); }
        acc = __builtin_amdgcn_mfma_f32_32x32x16_bf16(a, w, acc, 0, 0, 0);
    }

    short* mrow = Mt + (size_t)b * EMB * EMB + (size_t)(e0 + l31) * EMB + h * 32;
    #pragma unroll
    for (int r4 = 0; r4 < 4; r4++) {
        const int dbase = 8 * r4 + 4 * q;
        short4 s4 = make_short4(f2b(acc[r4 * 4 + 0]), f2b(acc[r4 * 4 + 1]),
                                f2b(acc[r4 * 4 + 2]), f2b(acc[r4 * 4 + 3]));
        *(short4*)(mrow + dbase) = s4;
    }
}

// ---------------------------------------------------------------------------
// out_kernel — register-prefetch pipeline; R5: plain launch_bounds (spill fix)
// + grid transposed (tn fast) like qkv.
// ---------------------------------------------------------------------------
__launch_bounds__(256)
__global__ void out_kernel(const short* __restrict__ Qf,
                           const float* __restrict__ Ksum,
                           const short* __restrict__ Mt,
                           float* __restrict__ Out) {
    __shared__ __align__(16) short As[128 * LDP];
    __shared__ __align__(16) short Bs[128 * LDP];
    __shared__ float zs[128][NHD];
    __shared__ float ksl[EMB];

    const int tid  = threadIdx.x;
    const int tn   = blockIdx.x;    // fast dim
    const int tm   = blockIdx.y;
    const int b    = (tm * 128) / SEQ;
    const int lane = tid & 63;
    const int wave = tid >> 6;
    const int wm   = (wave & 1) << 6;
    const int wn   = (wave >> 1) << 6;
    const int fr   = lane & 15;
    const int fq   = lane >> 4;

    ksl[tid] = Ksum[b * EMB + tid];
    __syncthreads();

    {
        const int t  = tid >> 1;
        const int h0 = (tid & 1) * 4;
        const short* qrow = Qf + (size_t)(tm * 128 + t) * EMB;
        #pragma unroll
        for (int hh = 0; hh < 4; hh++) {
            const int h = h0 + hh;
            float d = 0.f;
            #pragma unroll
            for (int u = 0; u < 8; u++) {
                short4 q4 = *(const short4*)(qrow + h * 32 + 4 * u);
                d += b2f(q4.x) * ksl[h * 32 + 4 * u + 0] + b2f(q4.y) * ksl[h * 32 + 4 * u + 1]
                   + b2f(q4.z) * ksl[h * 32 + 4 * u + 2] + b2f(q4.w) * ksl[h * 32 + 4 * u + 3];
            }
            zs[t][h] = (float)SEQ / (d + 1e-6f);
        }
    }
    __syncthreads();

    floatx4 acc[4][4];
    #pragma unroll
    for (int i = 0; i < 4; i++)
        #pragma unroll
        for (int j = 0; j < 4; j++)
            #pragma unroll
            for (int r = 0; r < 4; r++) acc[i][j][r] = 0.f;

    const short* Ab = Qf + (size_t)(tm * 128) * EMB;
    const short* Bb = Mt + (size_t)b * EMB * EMB + (size_t)(tn * 128) * EMB;

    short8 pq[4], pm[4];
    auto loadQM = [&](int kc) {
        const int kb = kc * 64;
        #pragma unroll
        for (int u = 0; u < 4; u++) {
            const int g = u * 256 + tid;
            const int row = g >> 3, c8 = (g & 7) * 8;
            pq[u] = *(const short8*)(Ab + (size_t)row * EMB + kb + c8);
            pm[u] = *(const short8*)(Bb + (size_t)row * EMB + kb + c8);
        }
    };

    loadQM(0);
    for (int kc = 0; kc < 4; kc++) {
        const int kb = kc * 64;
        #pragma unroll
        for (int u = 0; u < 4; u++) {
            const int g = u * 256 + tid;
            const int row = g >> 3, c8 = (g & 7) * 8;
            const float z = zs[row][(kb + c8) >> 5];
            short8 oa;
            #pragma unroll
            for (int t = 0; t < 8; t++) oa[t] = f2b(b2f(pq[u][t]) * z);
            *(short8*)&As[row * LDP + c8] = oa;
            *(short8*)&Bs[row * LDP + c8] = pm[u];
        }
        if (kc < 3) loadQM(kc + 1);
        lds_barrier();
        #pragma unroll
        for (int kk = 0; kk < 64; kk += 32) {
            short8 a[4], bb[4];
            #pragma unroll
            for (int i = 0; i < 4; i++)
                a[i] = *(const short8*)&As[(wm + i * 16 + fr) * LDP + kk + fq * 8];
            #pragma unroll
            for (int j = 0; j < 4; j++)
                bb[j] = *(const short8*)&Bs[(wn + j * 16 + fr) * LDP + kk + fq * 8];
            #pragma unroll
            for (int i = 0; i < 4; i++)
                #pragma unroll
                for (int j = 0; j < 4; j++)
                    acc[i][j] = __builtin_amdgcn_mfma_f32_16x16x32_bf16(a[i], bb[j], acc[i][j], 0, 0, 0);
        }
        lds_barrier();
    }

    const int row0 = tm * 128;
    #pragma unroll
    for (int i = 0; i < 4; i++) {
        #pragma unroll
        for (int j = 0; j < 4; j++) {
            const int colg = tn * 128 + wn + j * 16 + fr;
            #pragma unroll
            for (int rr = 0; rr < 4; rr++) {
                const int rowg = row0 + wm + i * 16 + fq * 4 + rr;
                Out[(size_t)rowg * EMB + colg] = acc[i][j][rr];
            }
        }
    }
}

extern "C" void kernel_launch(void* const* d_in, const int* in_sizes, int n_in,
                              void* d_out, int out_size, void* d_ws, size_t ws_size,
                              hipStream_t stream) {
    (void)in_sizes; (void)n_in; (void)out_size;
    const float* q  = (const float*)d_in[0];
    const float* k  = (const float*)d_in[1];
    const float* v  = (const float*)d_in[2];
    const float* Wq = (const float*)d_in[3];
    const float* bq = (const float*)d_in[4];
    const float* Wk = (const float*)d_in[5];
    const float* bk = (const float*)d_in[6];
    const float* Wv = (const float*)d_in[7];
    const float* bv = (const float*)d_in[8];
    const float* Wm = (const float*)d_in[9];

    char* ws = (char*)d_ws;
    short* Qf   = (short*)(ws);                                   // 32 MB bf16
    short* Kf   = (short*)(ws + 33554432);                        // 32 MB bf16
    short* Vn   = (short*)(ws + 67108864);                        // 32 MB bf16
    float* Ksum = (float*)(ws + 100663296);                       // 8 KB
    float* KV   = (float*)(ws + 100663296 + 8192);                // 256 KB
    short* Mt   = (short*)(ws + 100663296 + 8192 + 262144);       // 1 MB bf16
    // Wb (384 KB) overlays Mt: wconv writes -> qkv reads -> m_kernel overwrites
    // Mt -> out reads Mt. Strictly stream-ordered.
    short* Wb   = (short*)(ws + 100663296 + 8192 + 262144);
    const size_t kvp_off = 100663296ull + 8192 + 262144 + 1048576;
    float* KVp  = (float*)(ws + kvp_off);                         // kvsp*256 KB

    int kvsp = 0;
    if      (ws_size >= kvp_off + 64ull * 262144) kvsp = 64;
    else if (ws_size >= kvp_off + 32ull * 262144) kvsp = 32;
    else if (ws_size >= kvp_off + 16ull * 262144) kvsp = 16;

    hipMemsetAsync(ws + 100663296, 0, 8192 + 262144, stream);

    dim3 blk(256);
    wconv_kernel<<<dim3(32, 3), blk, 0, stream>>>(Wq, Wk, Wv, Wb);
    qkv_kernel<<<dim3(2, 512, 3), blk, 0, stream>>>(q, k, v, Wb, bq, bk, bv,
                                                    Qf, Kf, Vn, Ksum);

    if (kvsp) {
        kv_kernel<false><<<NB * kvsp, 256, 0, stream>>>(Kf, Vn, KVp, kvsp);
        kvred_kernel<<<64, 256, 0, stream>>>(KVp, KV, kvsp);
    } else {
        kv_kernel<true><<<NB * 16, 256, 0, stream>>>(Kf, Vn, KV, 16);
    }

    m_kernel<<<512, 64, 0, stream>>>(KV, Wm, Mt);
    out_kernel<<<dim3(2, 512), blk, 0, stream>>>(Qf, Ksum, Mt, (float*)d_out);
}